// Round 1
// baseline (3865.104 us; speedup 1.0000x reference)
//
#include <hip/hip_runtime.h>
#include <math.h>

// MACE-like GNN forward on MI355X. All f32 (no fp32 MFMA on CDNA4; bf16 MFMA
// deferred pending accuracy check). Structure:
//   k_edge_geom : per-edge unit vec, sph harmonics Y[E,16], radial feats[E,8]
//   k_h_init    : h[N,16,64]=0 except h[:,0,:]=W_embed[species]; node_es=E0
//   per layer l:
//     memset A
//     k_radial  : 3-layer silu MLP feats->64->64->64  (weights in LDS)
//     k_message : R = T3 @ rWout (tiled, 16 edges/block, 4 cols/thread),
//                 m = R*Y*h_src, atomicAdd into A[dst]  (THE heavy kernel)
//     k_update0 / k_update1 : sc (row-0 only), inv2/inv3, h update, readout
//   k_reduce    : node_es -> per-graph energy via LDS bins
//
// ws requirement: ~237 MB.

#define NN 16384
#define NE 131072
#define NZ 10
#define NG 64

__device__ __forceinline__ float silu_f(float x) {
    return x / (1.0f + __expf(-x));
}

__global__ __launch_bounds__(256) void k_edge_geom(
    const float* __restrict__ pos, const int* __restrict__ ei,
    float* __restrict__ Y, float* __restrict__ feats)
{
    int e = blockIdx.x * 256 + threadIdx.x;
    if (e >= NE) return;
    int s = ei[e];
    int d = ei[NE + e];
    float vx = pos[d*3+0] - pos[s*3+0];
    float vy = pos[d*3+1] - pos[s*3+1];
    float vz = pos[d*3+2] - pos[s*3+2];
    float len = sqrtf(vx*vx + vy*vy + vz*vz + 1e-12f);
    float inv = 1.0f / len;
    float x = vx*inv, y = vy*inv, z = vz*inv;

    const float s3 = 1.7320508075688772f, s5 = 2.2360679774997896f;
    const float s7 = 2.6457513110645907f, s15 = 3.872983346207417f;
    const float s21 = 4.58257569495584f, s35 = 5.916079783099616f;
    const float s105 = 10.246950765959598f;
    float xx = x*x, yy = y*y, zz = z*z;
    float* Ye = Y + (size_t)e*16;
    Ye[0] = 1.0f;
    Ye[1] = s3*x; Ye[2] = s3*y; Ye[3] = s3*z;
    Ye[4] = s15*x*y; Ye[5] = s15*y*z; Ye[6] = 0.5f*s5*(3.0f*zz - 1.0f);
    Ye[7] = s15*x*z; Ye[8] = 0.5f*s15*(xx - yy);
    Ye[9]  = 0.25f*s35*y*(3.0f*xx - yy);
    Ye[10] = 0.5f*s105*x*y*z;
    Ye[11] = 0.25f*s21*y*(5.0f*zz - 1.0f);
    Ye[12] = 0.5f*s7*z*(5.0f*zz - 3.0f);
    Ye[13] = 0.25f*s21*x*(5.0f*zz - 1.0f);
    Ye[14] = 0.25f*s105*z*(xx - yy);
    Ye[15] = 0.25f*s35*x*(xx - 3.0f*yy);

    // radial: bessel * poly cutoff (p=5), RMAX=5
    float u = len * 0.2f;
    float safe = fmaxf(len, 1e-6f);
    float u5 = u*u; u5 = u5*u5*u;             // u^5
    float env = 1.0f - 21.0f*u5 + 35.0f*u5*u - 15.0f*u5*u*u;
    env = (u < 1.0f) ? env : 0.0f;
    float c = 0.6324555320336759f * env / safe;   // sqrt(2/5)
    float* fe = feats + (size_t)e*8;
    const float PI = 3.14159265358979323846f;
    #pragma unroll
    for (int n = 1; n <= 8; n++)
        fe[n-1] = c * __sinf((float)n * PI * u);
}

__global__ __launch_bounds__(256) void k_h_init(
    const float* __restrict__ W_embed, const float* __restrict__ ae,
    const int* __restrict__ species, float* __restrict__ h,
    float* __restrict__ node_es)
{
    int i = blockIdx.x * 256 + threadIdx.x;   // over N*1024
    int n = i >> 10, r = i & 1023;
    int sp = species[n];
    h[i] = (r < 64) ? W_embed[sp*64 + r] : 0.0f;
    if (r == 0) node_es[n] = ae[sp];
}

// 3-layer silu MLP per edge: feats[8] -> 64 -> 64 -> 64. One wave per edge.
__global__ __launch_bounds__(256) void k_radial(
    const float* __restrict__ feats, const float* __restrict__ rW1,
    const float* __restrict__ rW2, const float* __restrict__ rW3,
    float* __restrict__ T3)
{
    __shared__ float w1[8*64];
    __shared__ float w2[64*64];
    __shared__ float w3[64*64];
    __shared__ float act[4][64];
    for (int i = threadIdx.x; i < 8*64; i += 256) w1[i] = rW1[i];
    for (int i = threadIdx.x; i < 64*64; i += 256) { w2[i] = rW2[i]; w3[i] = rW3[i]; }
    __syncthreads();
    int wave = threadIdx.x >> 6, lane = threadIdx.x & 63;
    for (int e0 = blockIdx.x * 4; e0 < NE; e0 += gridDim.x * 4) {
        int e = e0 + wave;
        const float* fe = feats + (size_t)e*8;
        float a = 0.f;
        #pragma unroll
        for (int i = 0; i < 8; i++) a = fmaf(fe[i], w1[i*64+lane], a);
        a = silu_f(a);
        act[wave][lane] = a;
        __syncthreads();
        float b = 0.f;
        #pragma unroll
        for (int i = 0; i < 64; i++) b = fmaf(act[wave][i], w2[i*64+lane], b);
        b = silu_f(b);
        __syncthreads();
        act[wave][lane] = b;
        __syncthreads();
        float cc = 0.f;
        #pragma unroll
        for (int i = 0; i < 64; i++) cc = fmaf(act[wave][i], w3[i*64+lane], cc);
        T3[(size_t)e*64 + lane] = silu_f(cc);
        __syncthreads();
    }
}

// R = T3 @ Wout per edge, m = R*Y*h_src, atomic scatter into A[dst].
// 16 edges per block; thread owns 4 consecutive output columns (float4 W load).
__global__ __launch_bounds__(256) void k_message(
    const float* __restrict__ T3, const float* __restrict__ Wout,
    const float* __restrict__ Y, const float* __restrict__ h,
    const int* __restrict__ ei, float* __restrict__ A)
{
    __shared__ __align__(16) float t3s[16][64];
    __shared__ __align__(16) float hs[16][64];
    __shared__ float ys[16][16];
    __shared__ int srcs[16];
    __shared__ int dsts[16];
    int tid = threadIdx.x;
    int e0 = blockIdx.x * 16;
    if (tid < 16) {
        srcs[tid] = ei[e0 + tid];
        dsts[tid] = ei[NE + e0 + tid];
    }
    __syncthreads();
    int row = tid >> 4, q = tid & 15;
    ((float4*)t3s[row])[q] = ((const float4*)(T3 + (size_t)(e0+row)*64))[q];
    ((float4*)hs[row])[q]  = ((const float4*)(h  + (size_t)srcs[row]*1024))[q];
    ys[row][q] = Y[(size_t)(e0+row)*16 + q];
    __syncthreads();

    float acc[16][4];
    #pragma unroll
    for (int e = 0; e < 16; e++)
        acc[e][0] = acc[e][1] = acc[e][2] = acc[e][3] = 0.f;

    const float* Wp = Wout + 4*tid;
    #pragma unroll 4
    for (int t = 0; t < 64; t++) {
        float4 w = *((const float4*)(Wp + (size_t)t*1024));
        #pragma unroll
        for (int e = 0; e < 16; e++) {
            float s = t3s[e][t];
            acc[e][0] = fmaf(s, w.x, acc[e][0]);
            acc[e][1] = fmaf(s, w.y, acc[e][1]);
            acc[e][2] = fmaf(s, w.z, acc[e][2]);
            acc[e][3] = fmaf(s, w.w, acc[e][3]);
        }
    }
    int k = tid >> 4;          // (4*tid)>>6 — all 4 cols share one k
    int f0 = (4*tid) & 63;
    #pragma unroll
    for (int e = 0; e < 16; e++) {
        float yk = ys[e][k] * 0.125f;   // /AVG folded in
        float* Ap = A + (size_t)dsts[e]*1024 + 4*tid;
        atomicAdd(Ap+0, acc[e][0]*yk*hs[e][f0+0]);
        atomicAdd(Ap+1, acc[e][1]*yk*hs[e][f0+1]);
        atomicAdd(Ap+2, acc[e][2]*yk*hs[e][f0+2]);
        atomicAdd(Ap+3, acc[e][3]*yk*hs[e][f0+3]);
    }
}

// l=0 node update: h old is zero except row 0 -> sc only row 0.
__global__ __launch_bounds__(256) void k_update0(
    const float* __restrict__ A, const float* __restrict__ h,
    const float* __restrict__ Wsc, const float* __restrict__ pw,
    const float* __restrict__ read1_w, const int* __restrict__ species,
    float* __restrict__ h2, float* __restrict__ node_es)
{
    __shared__ float h0s[4][64];
    int wave = threadIdx.x >> 6, lane = threadIdx.x & 63;
    int n = blockIdx.x * 4 + wave;
    h0s[wave][lane] = h[(size_t)n*1024 + lane];
    __syncthreads();
    int sp = species[n];
    const float* W = Wsc + (size_t)sp*4096;
    float sc0 = 0.f;
    #pragma unroll
    for (int c = 0; c < 64; c++) sc0 = fmaf(h0s[wave][c], W[c*64+lane], sc0);
    float a[16], inv2 = 0.f;
    #pragma unroll
    for (int k = 0; k < 16; k++) {
        a[k] = A[(size_t)n*1024 + k*64 + lane];
        inv2 = fmaf(a[k], a[k], inv2);
    }
    float inv3 = inv2 * a[0];
    float p0 = pw[lane], p1 = pw[64+lane], p2 = pw[128+lane];
    float hn0 = a[0]*p0 + inv2*p1 + inv3*p2 + sc0;
    h2[(size_t)n*1024 + lane] = hn0;
    #pragma unroll
    for (int k = 1; k < 16; k++)
        h2[(size_t)n*1024 + k*64 + lane] = a[k]*p0;
    float r = hn0 * read1_w[lane];
    #pragma unroll
    for (int off = 32; off; off >>= 1) r += __shfl_down(r, off, 64);
    if (lane == 0) node_es[n] += r;
}

// l=1: only node_es contribution needed (h_new row 0 -> nonlinear readout).
__global__ __launch_bounds__(256) void k_update1(
    const float* __restrict__ A, const float* __restrict__ h,
    const float* __restrict__ Wsc, const float* __restrict__ pw,
    const float* __restrict__ Wa, const float* __restrict__ wb,
    const int* __restrict__ species, float* __restrict__ node_es)
{
    __shared__ float h0s[4][64];
    __shared__ float hns[4][64];
    int wave = threadIdx.x >> 6, lane = threadIdx.x & 63;
    int n = blockIdx.x * 4 + wave;
    h0s[wave][lane] = h[(size_t)n*1024 + lane];
    __syncthreads();
    int sp = species[n];
    const float* W = Wsc + (size_t)sp*4096;
    float sc0 = 0.f;
    #pragma unroll
    for (int c = 0; c < 64; c++) sc0 = fmaf(h0s[wave][c], W[c*64+lane], sc0);
    float a[16], inv2 = 0.f;
    #pragma unroll
    for (int k = 0; k < 16; k++) {
        a[k] = A[(size_t)n*1024 + k*64 + lane];
        inv2 = fmaf(a[k], a[k], inv2);
    }
    float inv3 = inv2 * a[0];
    float hn0 = a[0]*pw[lane] + inv2*pw[64+lane] + inv3*pw[128+lane] + sc0;
    hns[wave][lane] = hn0;
    __syncthreads();
    float contrib = 0.f;
    if (lane < 16) {
        float aj = 0.f;
        #pragma unroll
        for (int f = 0; f < 64; f++) aj = fmaf(hns[wave][f], Wa[f*16+lane], aj);
        contrib = silu_f(aj) * wb[lane];
    }
    #pragma unroll
    for (int off = 8; off; off >>= 1) contrib += __shfl_down(contrib, off, 64);
    if (lane == 0) node_es[n] += contrib;
}

__global__ __launch_bounds__(256) void k_reduce(
    const float* __restrict__ node_es, const int* __restrict__ batch,
    float* __restrict__ out)
{
    __shared__ float bins[NG];
    if (threadIdx.x < NG) bins[threadIdx.x] = 0.f;
    __syncthreads();
    for (int n = blockIdx.x*256 + threadIdx.x; n < NN; n += gridDim.x*256)
        atomicAdd(&bins[batch[n]], node_es[n]);
    __syncthreads();
    if (threadIdx.x < NG) atomicAdd(&out[threadIdx.x], bins[threadIdx.x]);
}

extern "C" void kernel_launch(void* const* d_in, const int* in_sizes, int n_in,
                              void* d_out, int out_size, void* d_ws, size_t ws_size,
                              hipStream_t stream)
{
    const float* positions = (const float*)d_in[0];
    const float* atomic_energies = (const float*)d_in[1];
    const float* W_embed  = (const float*)d_in[2];
    const float* rW1      = (const float*)d_in[3];
    const float* rW2      = (const float*)d_in[4];
    const float* rW3      = (const float*)d_in[5];
    const float* rWout    = (const float*)d_in[6];
    const float* Wsc      = (const float*)d_in[7];
    const float* pw       = (const float*)d_in[8];
    const float* read1_w  = (const float*)d_in[9];
    const float* read2_Wa = (const float*)d_in[10];
    const float* read2_wb = (const float*)d_in[11];
    const int* species    = (const int*)d_in[12];
    const int* edge_index = (const int*)d_in[13];
    const int* batch      = (const int*)d_in[14];
    float* out = (float*)d_out;

    char* w = (char*)d_ws;
    float* Y     = (float*)w;  w += (size_t)NE*16*4;
    float* feats = (float*)w;  w += (size_t)NE*8*4;
    float* T3    = (float*)w;  w += (size_t)NE*64*4;
    float* h     = (float*)w;  w += (size_t)NN*1024*4;
    float* h2    = (float*)w;  w += (size_t)NN*1024*4;
    float* A     = (float*)w;  w += (size_t)NN*1024*4;
    float* node_es = (float*)w; w += (size_t)NN*4;

    k_edge_geom<<<NE/256, 256, 0, stream>>>(positions, edge_index, Y, feats);
    k_h_init<<<NN*1024/256, 256, 0, stream>>>(W_embed, atomic_energies, species, h, node_es);

    // layer 0
    hipMemsetAsync(A, 0, (size_t)NN*1024*4, stream);
    k_radial<<<2048, 256, 0, stream>>>(feats, rW1, rW2, rW3, T3);
    k_message<<<NE/16, 256, 0, stream>>>(T3, rWout, Y, h, edge_index, A);
    k_update0<<<NN/4, 256, 0, stream>>>(A, h, Wsc, pw, read1_w, species, h2, node_es);

    // layer 1
    hipMemsetAsync(A, 0, (size_t)NN*1024*4, stream);
    k_radial<<<2048, 256, 0, stream>>>(feats, rW1 + 8*64, rW2 + 64*64, rW3 + 64*64, T3);
    k_message<<<NE/16, 256, 0, stream>>>(T3, rWout + 64*1024, Y, h2, edge_index, A);
    k_update1<<<NN/4, 256, 0, stream>>>(A, h2, Wsc + 10*4096, pw + 192,
                                        read2_Wa, read2_wb, species, node_es);

    hipMemsetAsync(d_out, 0, NG*sizeof(float), stream);
    k_reduce<<<64, 256, 0, stream>>>(node_es, batch, out);
}

// Round 2
// 924.174 us; speedup vs baseline: 4.1822x; 4.1822x over previous
//
#include <hip/hip_runtime.h>
#include <math.h>

// MACE-like GNN forward on MI355X, round 2.
// Round-1 finding: k_message was atomic-write-bound (WRITE_SIZE 2.1 GB/dispatch,
// 4x amplification of 4B device atomics; dur == bytes / 1.26 TB/s).
// Fix: counting-sort edges by dst; k_message walks sorted edges, accumulates
// runs of equal dst in registers, flushes interior runs as plain float4 stores
// (exclusively owned), boundary runs via atomicAdd. Also: h / h2 only row 0 is
// ever consumed -> stored as [N,64] (kills 128 MB of dead writes).

#define NN 16384
#define NE 131072
#define NZ 10
#define NG 64

__device__ __forceinline__ float silu_f(float x) {
    return x / (1.0f + __expf(-x));
}

// ---- sort by dst: count -> scan -> fill ------------------------------------
__global__ __launch_bounds__(256) void k_count(
    const int* __restrict__ ei, int* __restrict__ deg)
{
    int e = blockIdx.x * 256 + threadIdx.x;
    if (e < NE) atomicAdd(&deg[ei[NE + e]], 1);
}

__global__ __launch_bounds__(256) void k_scan(
    const int* __restrict__ deg, int* __restrict__ cursor)
{
    __shared__ int part[256];
    int t = threadIdx.x;
    int base = t * 64;
    int s = 0;
    for (int i = 0; i < 64; i++) s += deg[base + i];
    part[t] = s;
    __syncthreads();
    for (int off = 1; off < 256; off <<= 1) {
        int v = (t >= off) ? part[t - off] : 0;
        __syncthreads();
        part[t] += v;
        __syncthreads();
    }
    int run = (t > 0) ? part[t - 1] : 0;
    for (int i = 0; i < 64; i++) { cursor[base + i] = run; run += deg[base + i]; }
}

__global__ __launch_bounds__(256) void k_fill(
    const int* __restrict__ ei, int* __restrict__ cursor,
    int* __restrict__ sSrc, int* __restrict__ sDst)
{
    int e = blockIdx.x * 256 + threadIdx.x;
    if (e >= NE) return;
    int d = ei[NE + e];
    int p = atomicAdd(&cursor[d], 1);
    sSrc[p] = ei[e];
    sDst[p] = d;
}

// ---- per-edge geometry (operates in sorted order; Y/feats contiguous) ------
__global__ __launch_bounds__(256) void k_edge_geom(
    const float* __restrict__ pos, const int* __restrict__ sSrc,
    const int* __restrict__ sDst, float* __restrict__ Y, float* __restrict__ feats)
{
    int e = blockIdx.x * 256 + threadIdx.x;
    if (e >= NE) return;
    int s = sSrc[e];
    int d = sDst[e];
    float vx = pos[d*3+0] - pos[s*3+0];
    float vy = pos[d*3+1] - pos[s*3+1];
    float vz = pos[d*3+2] - pos[s*3+2];
    float len = sqrtf(vx*vx + vy*vy + vz*vz + 1e-12f);
    float inv = 1.0f / len;
    float x = vx*inv, y = vy*inv, z = vz*inv;

    const float s3 = 1.7320508075688772f, s5 = 2.2360679774997896f;
    const float s7 = 2.6457513110645907f, s15 = 3.872983346207417f;
    const float s21 = 4.58257569495584f, s35 = 5.916079783099616f;
    const float s105 = 10.246950765959598f;
    float xx = x*x, yy = y*y, zz = z*z;
    float* Ye = Y + (size_t)e*16;
    Ye[0] = 1.0f;
    Ye[1] = s3*x; Ye[2] = s3*y; Ye[3] = s3*z;
    Ye[4] = s15*x*y; Ye[5] = s15*y*z; Ye[6] = 0.5f*s5*(3.0f*zz - 1.0f);
    Ye[7] = s15*x*z; Ye[8] = 0.5f*s15*(xx - yy);
    Ye[9]  = 0.25f*s35*y*(3.0f*xx - yy);
    Ye[10] = 0.5f*s105*x*y*z;
    Ye[11] = 0.25f*s21*y*(5.0f*zz - 1.0f);
    Ye[12] = 0.5f*s7*z*(5.0f*zz - 3.0f);
    Ye[13] = 0.25f*s21*x*(5.0f*zz - 1.0f);
    Ye[14] = 0.25f*s105*z*(xx - yy);
    Ye[15] = 0.25f*s35*x*(xx - 3.0f*yy);

    float u = len * 0.2f;
    float safe = fmaxf(len, 1e-6f);
    float u5 = u*u; u5 = u5*u5*u;
    float env = 1.0f - 21.0f*u5 + 35.0f*u5*u - 15.0f*u5*u*u;
    env = (u < 1.0f) ? env : 0.0f;
    float c = 0.6324555320336759f * env / safe;   // sqrt(2/5)
    float* fe = feats + (size_t)e*8;
    const float PI = 3.14159265358979323846f;
    #pragma unroll
    for (int n = 1; n <= 8; n++)
        fe[n-1] = c * __sinf((float)n * PI * u);
}

// ---- h init: h0[N,64] = W_embed[species]; node_es = atomic energies --------
__global__ __launch_bounds__(256) void k_h_init(
    const float* __restrict__ W_embed, const float* __restrict__ ae,
    const int* __restrict__ species, float* __restrict__ h0,
    float* __restrict__ node_es)
{
    int i = blockIdx.x * 256 + threadIdx.x;   // over N*64
    int n = i >> 6, r = i & 63;
    int sp = species[n];
    h0[i] = W_embed[sp*64 + r];
    if (r == 0) node_es[n] = ae[sp];
}

// ---- radial MLP: feats[8]->64->64->64, one wave per edge -------------------
__global__ __launch_bounds__(256) void k_radial(
    const float* __restrict__ feats, const float* __restrict__ rW1,
    const float* __restrict__ rW2, const float* __restrict__ rW3,
    float* __restrict__ T3)
{
    __shared__ float w1[8*64];
    __shared__ float w2[64*64];
    __shared__ float w3[64*64];
    __shared__ float act[4][64];
    for (int i = threadIdx.x; i < 8*64; i += 256) w1[i] = rW1[i];
    for (int i = threadIdx.x; i < 64*64; i += 256) { w2[i] = rW2[i]; w3[i] = rW3[i]; }
    __syncthreads();
    int wave = threadIdx.x >> 6, lane = threadIdx.x & 63;
    for (int e0 = blockIdx.x * 4; e0 < NE; e0 += gridDim.x * 4) {
        int e = e0 + wave;
        const float* fe = feats + (size_t)e*8;
        float a = 0.f;
        #pragma unroll
        for (int i = 0; i < 8; i++) a = fmaf(fe[i], w1[i*64+lane], a);
        a = silu_f(a);
        act[wave][lane] = a;
        __syncthreads();
        float b = 0.f;
        #pragma unroll
        for (int i = 0; i < 64; i++) b = fmaf(act[wave][i], w2[i*64+lane], b);
        b = silu_f(b);
        __syncthreads();
        act[wave][lane] = b;
        __syncthreads();
        float cc = 0.f;
        #pragma unroll
        for (int i = 0; i < 64; i++) cc = fmaf(act[wave][i], w3[i*64+lane], cc);
        T3[(size_t)e*64 + lane] = silu_f(cc);
        __syncthreads();
    }
}

// ---- message + scatter over sorted edges -----------------------------------
// Block = 64 sorted edges, 4 sub-batches of 16. Register run-accumulation per
// distinct dst; interior runs -> float4 store, boundary runs -> atomicAdd.
__global__ __launch_bounds__(256) void k_message(
    const float* __restrict__ T3, const float* __restrict__ Wout,
    const float* __restrict__ Y, const float* __restrict__ h,
    const int* __restrict__ sSrc, const int* __restrict__ sDst,
    float* __restrict__ A)
{
    __shared__ __align__(16) float t3s[16][64];
    __shared__ __align__(16) float hs[16][64];
    __shared__ float ys[16][16];
    __shared__ int srcs[16];
    __shared__ int dsts[16];
    int tid = threadIdx.x;
    int row = tid >> 4, q = tid & 15;
    int k = tid >> 4, f0 = (4*tid) & 63;
    int tile0 = blockIdx.x * 64;

    float run0 = 0.f, run1 = 0.f, run2 = 0.f, run3 = 0.f;
    int run_start = 0, prev_d = -1;

    for (int sb = 0; sb < 4; sb++) {
        int g0 = tile0 + sb*16;
        __syncthreads();   // protect LDS from previous sub-batch's merge readers
        if (tid < 16) { srcs[tid] = sSrc[g0 + tid]; dsts[tid] = sDst[g0 + tid]; }
        __syncthreads();
        ((float4*)t3s[row])[q] = ((const float4*)(T3 + (size_t)(g0+row)*64))[q];
        ((float4*)hs[row])[q]  = ((const float4*)(h  + (size_t)srcs[row]*64))[q];
        ys[row][q] = Y[(size_t)(g0+row)*16 + q];
        __syncthreads();

        float acc[16][4];
        #pragma unroll
        for (int e = 0; e < 16; e++)
            acc[e][0] = acc[e][1] = acc[e][2] = acc[e][3] = 0.f;

        const float* Wp = Wout + 4*tid;
        #pragma unroll 4
        for (int t = 0; t < 64; t++) {
            float4 w = *((const float4*)(Wp + (size_t)t*1024));
            #pragma unroll
            for (int e = 0; e < 16; e++) {
                float s = t3s[e][t];
                acc[e][0] = fmaf(s, w.x, acc[e][0]);
                acc[e][1] = fmaf(s, w.y, acc[e][1]);
                acc[e][2] = fmaf(s, w.z, acc[e][2]);
                acc[e][3] = fmaf(s, w.w, acc[e][3]);
            }
        }

        // merge into dst-runs (dst uniform across block -> uniform branches)
        #pragma unroll
        for (int e = 0; e < 16; e++) {
            int g = sb*16 + e;
            int d = dsts[e];
            if (g == 0) {
                prev_d = d;
            } else if (d != prev_d) {
                float* Ap = A + (size_t)prev_d*1024 + 4*tid;
                if (run_start == 0) {
                    atomicAdd(Ap+0, run0); atomicAdd(Ap+1, run1);
                    atomicAdd(Ap+2, run2); atomicAdd(Ap+3, run3);
                } else {
                    *(float4*)Ap = make_float4(run0, run1, run2, run3);
                }
                run0 = run1 = run2 = run3 = 0.f;
                run_start = g;
                prev_d = d;
            }
            float yk = ys[e][k] * 0.125f;   // /AVG folded in
            run0 = fmaf(acc[e][0]*yk, hs[e][f0+0], run0);
            run1 = fmaf(acc[e][1]*yk, hs[e][f0+1], run1);
            run2 = fmaf(acc[e][2]*yk, hs[e][f0+2], run2);
            run3 = fmaf(acc[e][3]*yk, hs[e][f0+3], run3);
        }
    }
    // final run may continue into the next tile -> always atomic
    float* Ap = A + (size_t)prev_d*1024 + 4*tid;
    atomicAdd(Ap+0, run0); atomicAdd(Ap+1, run1);
    atomicAdd(Ap+2, run2); atomicAdd(Ap+3, run3);
}

// ---- l=0 node update (sc row 0 only; h2 row 0 only is ever consumed) -------
__global__ __launch_bounds__(256) void k_update0(
    const float* __restrict__ A, const float* __restrict__ h0,
    const float* __restrict__ Wsc, const float* __restrict__ pw,
    const float* __restrict__ read1_w, const int* __restrict__ species,
    float* __restrict__ h2, float* __restrict__ node_es)
{
    __shared__ float h0s[4][64];
    int wave = threadIdx.x >> 6, lane = threadIdx.x & 63;
    int n = blockIdx.x * 4 + wave;
    h0s[wave][lane] = h0[(size_t)n*64 + lane];
    __syncthreads();
    int sp = species[n];
    const float* W = Wsc + (size_t)sp*4096;
    float sc0 = 0.f;
    #pragma unroll
    for (int c = 0; c < 64; c++) sc0 = fmaf(h0s[wave][c], W[c*64+lane], sc0);
    float a[16], inv2 = 0.f;
    #pragma unroll
    for (int kk = 0; kk < 16; kk++) {
        a[kk] = A[(size_t)n*1024 + kk*64 + lane];
        inv2 = fmaf(a[kk], a[kk], inv2);
    }
    float inv3 = inv2 * a[0];
    float hn0 = a[0]*pw[lane] + inv2*pw[64+lane] + inv3*pw[128+lane] + sc0;
    h2[(size_t)n*64 + lane] = hn0;
    float r = hn0 * read1_w[lane];
    #pragma unroll
    for (int off = 32; off; off >>= 1) r += __shfl_down(r, off, 64);
    if (lane == 0) node_es[n] += r;
}

// ---- l=1: only readout contribution needed ---------------------------------
__global__ __launch_bounds__(256) void k_update1(
    const float* __restrict__ A, const float* __restrict__ h2,
    const float* __restrict__ Wsc, const float* __restrict__ pw,
    const float* __restrict__ Wa, const float* __restrict__ wb,
    const int* __restrict__ species, float* __restrict__ node_es)
{
    __shared__ float h0s[4][64];
    __shared__ float hns[4][64];
    int wave = threadIdx.x >> 6, lane = threadIdx.x & 63;
    int n = blockIdx.x * 4 + wave;
    h0s[wave][lane] = h2[(size_t)n*64 + lane];
    __syncthreads();
    int sp = species[n];
    const float* W = Wsc + (size_t)sp*4096;
    float sc0 = 0.f;
    #pragma unroll
    for (int c = 0; c < 64; c++) sc0 = fmaf(h0s[wave][c], W[c*64+lane], sc0);
    float a[16], inv2 = 0.f;
    #pragma unroll
    for (int kk = 0; kk < 16; kk++) {
        a[kk] = A[(size_t)n*1024 + kk*64 + lane];
        inv2 = fmaf(a[kk], a[kk], inv2);
    }
    float inv3 = inv2 * a[0];
    float hn0 = a[0]*pw[lane] + inv2*pw[64+lane] + inv3*pw[128+lane] + sc0;
    hns[wave][lane] = hn0;
    __syncthreads();
    float contrib = 0.f;
    if (lane < 16) {
        float aj = 0.f;
        #pragma unroll
        for (int f = 0; f < 64; f++) aj = fmaf(hns[wave][f], Wa[f*16+lane], aj);
        contrib = silu_f(aj) * wb[lane];
    }
    #pragma unroll
    for (int off = 8; off; off >>= 1) contrib += __shfl_down(contrib, off, 64);
    if (lane == 0) node_es[n] += contrib;
}

__global__ __launch_bounds__(256) void k_reduce(
    const float* __restrict__ node_es, const int* __restrict__ batch,
    float* __restrict__ out)
{
    __shared__ float bins[NG];
    if (threadIdx.x < NG) bins[threadIdx.x] = 0.f;
    __syncthreads();
    for (int n = blockIdx.x*256 + threadIdx.x; n < NN; n += gridDim.x*256)
        atomicAdd(&bins[batch[n]], node_es[n]);
    __syncthreads();
    if (threadIdx.x < NG) atomicAdd(&out[threadIdx.x], bins[threadIdx.x]);
}

extern "C" void kernel_launch(void* const* d_in, const int* in_sizes, int n_in,
                              void* d_out, int out_size, void* d_ws, size_t ws_size,
                              hipStream_t stream)
{
    const float* positions = (const float*)d_in[0];
    const float* atomic_energies = (const float*)d_in[1];
    const float* W_embed  = (const float*)d_in[2];
    const float* rW1      = (const float*)d_in[3];
    const float* rW2      = (const float*)d_in[4];
    const float* rW3      = (const float*)d_in[5];
    const float* rWout    = (const float*)d_in[6];
    const float* Wsc      = (const float*)d_in[7];
    const float* pw       = (const float*)d_in[8];
    const float* read1_w  = (const float*)d_in[9];
    const float* read2_Wa = (const float*)d_in[10];
    const float* read2_wb = (const float*)d_in[11];
    const int* species    = (const int*)d_in[12];
    const int* edge_index = (const int*)d_in[13];
    const int* batch      = (const int*)d_in[14];
    float* out = (float*)d_out;

    char* w = (char*)d_ws;
    float* Y     = (float*)w;  w += (size_t)NE*16*4;
    float* feats = (float*)w;  w += (size_t)NE*8*4;
    float* T3    = (float*)w;  w += (size_t)NE*64*4;
    float* h0    = (float*)w;  w += (size_t)NN*64*4;
    float* h2    = (float*)w;  w += (size_t)NN*64*4;
    float* A     = (float*)w;  w += (size_t)NN*1024*4;
    float* node_es = (float*)w; w += (size_t)NN*4;
    int* deg     = (int*)w;    w += (size_t)NN*4;
    int* cursor  = (int*)w;    w += (size_t)NN*4;
    int* sSrc    = (int*)w;    w += (size_t)NE*4;
    int* sDst    = (int*)w;    w += (size_t)NE*4;

    // ---- counting sort by dst
    hipMemsetAsync(deg, 0, (size_t)NN*4, stream);
    k_count<<<NE/256, 256, 0, stream>>>(edge_index, deg);
    k_scan<<<1, 256, 0, stream>>>(deg, cursor);
    k_fill<<<NE/256, 256, 0, stream>>>(edge_index, cursor, sSrc, sDst);

    k_edge_geom<<<NE/256, 256, 0, stream>>>(positions, sSrc, sDst, Y, feats);
    k_h_init<<<NN*64/256, 256, 0, stream>>>(W_embed, atomic_energies, species, h0, node_es);

    // layer 0
    hipMemsetAsync(A, 0, (size_t)NN*1024*4, stream);
    k_radial<<<2048, 256, 0, stream>>>(feats, rW1, rW2, rW3, T3);
    k_message<<<NE/64, 256, 0, stream>>>(T3, rWout, Y, h0, sSrc, sDst, A);
    k_update0<<<NN/4, 256, 0, stream>>>(A, h0, Wsc, pw, read1_w, species, h2, node_es);

    // layer 1
    hipMemsetAsync(A, 0, (size_t)NN*1024*4, stream);
    k_radial<<<2048, 256, 0, stream>>>(feats, rW1 + 8*64, rW2 + 64*64, rW3 + 64*64, T3);
    k_message<<<NE/64, 256, 0, stream>>>(T3, rWout + 64*1024, Y, h2, sSrc, sDst, A);
    k_update1<<<NN/4, 256, 0, stream>>>(A, h2, Wsc + 10*4096, pw + 192,
                                        read2_Wa, read2_wb, species, node_es);

    hipMemsetAsync(d_out, 0, NG*sizeof(float), stream);
    k_reduce<<<64, 256, 0, stream>>>(node_es, batch, out);
}

// Round 7
// 726.620 us; speedup vs baseline: 5.3193x; 1.2719x over previous
//
#include <hip/hip_runtime.h>
#include <math.h>

// MACE-like GNN forward on MI355X, round 3 (4th resubmit — rounds 3-6 never
// ran: GPUAcquisitionTimeout at the broker; no compile/validate/profile yet).
// Round-2 finding: k_message VALUBusy 50% — half the issue slots were scalar
// ds_read_b32 of t3s (1024 reads/tile). Fix: T3@Wout via MFMA bf16x3 split
// (ahbh+albh+ahbl, ~2^-18 rel err). Wout pre-packed into fragment-linear
// bf16 hi/lo (k_wprep). D-frags scaled by Y*h/8, transposed through padded
// LDS (stride 518 -> conflict-free), then the round-2 run-merge (2 passes of
// 512 cols). k_radial: per-iter barriers removed (act is per-wave).

#define NN 16384
#define NE 131072
#define NZ 10
#define NG 64

typedef __attribute__((ext_vector_type(8))) short bf16x8;
typedef __attribute__((ext_vector_type(4))) float f32x4;

__device__ __forceinline__ float silu_f(float x) {
    return x / (1.0f + __expf(-x));
}

__device__ __forceinline__ unsigned short f2bf_rne(float x) {
    unsigned int u = __float_as_uint(x);
    unsigned int r = (u + 0x7FFFu + ((u >> 16) & 1u)) >> 16;
    return (unsigned short)r;
}
__device__ __forceinline__ float bf2f(unsigned short b) {
    return __uint_as_float(((unsigned int)b) << 16);
}

// ---- sort by dst: count -> scan -> fill ------------------------------------
__global__ __launch_bounds__(256) void k_count(
    const int* __restrict__ ei, int* __restrict__ deg)
{
    int e = blockIdx.x * 256 + threadIdx.x;
    if (e < NE) atomicAdd(&deg[ei[NE + e]], 1);
}

__global__ __launch_bounds__(256) void k_scan(
    const int* __restrict__ deg, int* __restrict__ cursor)
{
    __shared__ int part[256];
    int t = threadIdx.x;
    int base = t * 64;
    int s = 0;
    for (int i = 0; i < 64; i++) s += deg[base + i];
    part[t] = s;
    __syncthreads();
    for (int off = 1; off < 256; off <<= 1) {
        int v = (t >= off) ? part[t - off] : 0;
        __syncthreads();
        part[t] += v;
        __syncthreads();
    }
    int run = (t > 0) ? part[t - 1] : 0;
    for (int i = 0; i < 64; i++) { cursor[base + i] = run; run += deg[base + i]; }
}

__global__ __launch_bounds__(256) void k_fill(
    const int* __restrict__ ei, int* __restrict__ cursor,
    int* __restrict__ sSrc, int* __restrict__ sDst)
{
    int e = blockIdx.x * 256 + threadIdx.x;
    if (e >= NE) return;
    int d = ei[NE + e];
    int p = atomicAdd(&cursor[d], 1);
    sSrc[p] = ei[e];
    sDst[p] = d;
}

// ---- Wout -> MFMA fragment-linear bf16 hi/lo --------------------------------
// frag index = ((layer*2 + ks)*64 + nb)*64 + lane, elem j: value =
// Wout[layer][t = ks*32 + (lane>>4)*8 + j][col = nb*16 + (lane&15)].
__global__ __launch_bounds__(256) void k_wprep(
    const float* __restrict__ Wout, unsigned short* __restrict__ Bh,
    unsigned short* __restrict__ Bl)
{
    int idx = blockIdx.x * 256 + threadIdx.x;     // 16384 total
    int lane = idx & 63;
    int nb = (idx >> 6) & 63;
    int ks = (idx >> 12) & 1;
    int layer = idx >> 13;
    int col = nb * 16 + (lane & 15);
    int tbase = ks * 32 + ((lane >> 4) << 3);
    #pragma unroll
    for (int j = 0; j < 8; j++) {
        float v = Wout[(size_t)layer * 65536 + (size_t)(tbase + j) * 1024 + col];
        unsigned short hi = f2bf_rne(v);
        unsigned short lo = f2bf_rne(v - bf2f(hi));
        Bh[(size_t)idx * 8 + j] = hi;
        Bl[(size_t)idx * 8 + j] = lo;
    }
}

// ---- per-edge geometry ------------------------------------------------------
__global__ __launch_bounds__(256) void k_edge_geom(
    const float* __restrict__ pos, const int* __restrict__ sSrc,
    const int* __restrict__ sDst, float* __restrict__ Y, float* __restrict__ feats)
{
    int e = blockIdx.x * 256 + threadIdx.x;
    if (e >= NE) return;
    int s = sSrc[e];
    int d = sDst[e];
    float vx = pos[d*3+0] - pos[s*3+0];
    float vy = pos[d*3+1] - pos[s*3+1];
    float vz = pos[d*3+2] - pos[s*3+2];
    float len = sqrtf(vx*vx + vy*vy + vz*vz + 1e-12f);
    float inv = 1.0f / len;
    float x = vx*inv, y = vy*inv, z = vz*inv;

    const float s3 = 1.7320508075688772f, s5 = 2.2360679774997896f;
    const float s7 = 2.6457513110645907f, s15 = 3.872983346207417f;
    const float s21 = 4.58257569495584f, s35 = 5.916079783099616f;
    const float s105 = 10.246950765959598f;
    float xx = x*x, yy = y*y, zz = z*z;
    float* Ye = Y + (size_t)e*16;
    Ye[0] = 1.0f;
    Ye[1] = s3*x; Ye[2] = s3*y; Ye[3] = s3*z;
    Ye[4] = s15*x*y; Ye[5] = s15*y*z; Ye[6] = 0.5f*s5*(3.0f*zz - 1.0f);
    Ye[7] = s15*x*z; Ye[8] = 0.5f*s15*(xx - yy);
    Ye[9]  = 0.25f*s35*y*(3.0f*xx - yy);
    Ye[10] = 0.5f*s105*x*y*z;
    Ye[11] = 0.25f*s21*y*(5.0f*zz - 1.0f);
    Ye[12] = 0.5f*s7*z*(5.0f*zz - 3.0f);
    Ye[13] = 0.25f*s21*x*(5.0f*zz - 1.0f);
    Ye[14] = 0.25f*s105*z*(xx - yy);
    Ye[15] = 0.25f*s35*x*(xx - 3.0f*yy);

    float u = len * 0.2f;
    float safe = fmaxf(len, 1e-6f);
    float u5 = u*u; u5 = u5*u5*u;
    float env = 1.0f - 21.0f*u5 + 35.0f*u5*u - 15.0f*u5*u*u;
    env = (u < 1.0f) ? env : 0.0f;
    float c = 0.6324555320336759f * env / safe;   // sqrt(2/5)
    float* fe = feats + (size_t)e*8;
    const float PI = 3.14159265358979323846f;
    #pragma unroll
    for (int n = 1; n <= 8; n++)
        fe[n-1] = c * __sinf((float)n * PI * u);
}

// ---- h init -----------------------------------------------------------------
__global__ __launch_bounds__(256) void k_h_init(
    const float* __restrict__ W_embed, const float* __restrict__ ae,
    const int* __restrict__ species, float* __restrict__ h0,
    float* __restrict__ node_es)
{
    int i = blockIdx.x * 256 + threadIdx.x;   // over N*64
    int n = i >> 6, r = i & 63;
    int sp = species[n];
    h0[i] = W_embed[sp*64 + r];
    if (r == 0) node_es[n] = ae[sp];
}

// ---- radial MLP: feats[8]->64->64->64, one wave per edge -------------------
// act is per-wave: no per-iteration barriers needed (same-wave LDS RAW is
// ordered by lgkmcnt which the compiler inserts).
__global__ __launch_bounds__(256) void k_radial(
    const float* __restrict__ feats, const float* __restrict__ rW1,
    const float* __restrict__ rW2, const float* __restrict__ rW3,
    float* __restrict__ T3)
{
    __shared__ float w1[8*64];
    __shared__ float w2[64*64];
    __shared__ float w3[64*64];
    __shared__ float act[4][64];
    for (int i = threadIdx.x; i < 8*64; i += 256) w1[i] = rW1[i];
    for (int i = threadIdx.x; i < 64*64; i += 256) { w2[i] = rW2[i]; w3[i] = rW3[i]; }
    __syncthreads();
    int wave = threadIdx.x >> 6, lane = threadIdx.x & 63;
    for (int e0 = blockIdx.x * 4; e0 < NE; e0 += gridDim.x * 4) {
        int e = e0 + wave;
        const float* fe = feats + (size_t)e*8;
        float a = 0.f;
        #pragma unroll
        for (int i = 0; i < 8; i++) a = fmaf(fe[i], w1[i*64+lane], a);
        a = silu_f(a);
        act[wave][lane] = a;
        float b = 0.f;
        #pragma unroll
        for (int i = 0; i < 64; i++) b = fmaf(act[wave][i], w2[i*64+lane], b);
        b = silu_f(b);
        act[wave][lane] = b;
        float cc = 0.f;
        #pragma unroll
        for (int i = 0; i < 64; i++) cc = fmaf(act[wave][i], w3[i*64+lane], cc);
        T3[(size_t)e*64 + lane] = silu_f(cc);
    }
}

// ---- message via MFMA + transpose + run-merge ------------------------------
// Block = 256 thr (4 waves) = 64 contiguous sorted edges, 4 sub-tiles of 16.
// Per sub-tile: A frags from T3 (f32 -> bf16 hi/lo), B frags pre-packed;
// 2 passes of 512 cols: wave w computes nb = p*32 + w*8 + nbl, scales by
// Y*h/8, writes m into padded LDS, then all 256 threads run-merge (2 cols).
__global__ __launch_bounds__(256) void k_message(
    const float* __restrict__ T3, const unsigned short* __restrict__ Bh,
    const unsigned short* __restrict__ Bl, const float* __restrict__ Y,
    const float* __restrict__ h, const int* __restrict__ sSrc,
    const int* __restrict__ sDst, float* __restrict__ A)
{
    __shared__ float mbuf[16][518];     // stride 518: write groups on banks 0/24/16/8
    __shared__ float hs[16][64];
    __shared__ float ys[16][16];
    __shared__ int srcs[16];
    __shared__ int dsts[16];

    int tid = threadIdx.x;
    int lane = tid & 63;
    int w = tid >> 6;
    int tile0 = blockIdx.x * 64;
    const bf16x8* Bhf = (const bf16x8*)Bh;
    const bf16x8* Blf = (const bf16x8*)Bl;

    int prev_d = -1, run_start = 0;
    float r00 = 0.f, r01 = 0.f, r10 = 0.f, r11 = 0.f;  // pass0/pass1 run accum

    for (int sb = 0; sb < 4; sb++) {
        int g0 = tile0 + sb * 16;
        __syncthreads();                 // prev sub-tile's merge done
        if (tid < 16) { srcs[tid] = sSrc[g0 + tid]; dsts[tid] = sDst[g0 + tid]; }

        // A fragments from T3 (global, 32B/lane per kstep), bf16 hi/lo split
        const float* trow = T3 + (size_t)(g0 + (lane & 15)) * 64 + ((lane >> 4) << 3);
        float4 p0 = *(const float4*)(trow);
        float4 p1 = *(const float4*)(trow + 4);
        float4 p2 = *(const float4*)(trow + 32);
        float4 p3 = *(const float4*)(trow + 36);
        bf16x8 ah0, al0, ah1, al1;
        {
            float v[16] = {p0.x,p0.y,p0.z,p0.w, p1.x,p1.y,p1.z,p1.w,
                           p2.x,p2.y,p2.z,p2.w, p3.x,p3.y,p3.z,p3.w};
            #pragma unroll
            for (int j = 0; j < 8; j++) {
                unsigned short hi = f2bf_rne(v[j]);
                ah0[j] = (short)hi;
                al0[j] = (short)f2bf_rne(v[j] - bf2f(hi));
            }
            #pragma unroll
            for (int j = 0; j < 8; j++) {
                unsigned short hi = f2bf_rne(v[8+j]);
                ah1[j] = (short)hi;
                al1[j] = (short)f2bf_rne(v[8+j] - bf2f(hi));
            }
        }
        __syncthreads();                 // srcs visible
        {
            int row = tid >> 4, q = tid & 15;
            ((float4*)hs[row])[q] = ((const float4*)(h + (size_t)srcs[row] * 64))[q];
            ys[row][q] = Y[(size_t)(g0 + row) * 16 + q];
        }
        __syncthreads();                 // hs/ys visible

        // per-lane epilogue factors: edge = (lane>>4)*4 + r
        float hv[4][4];
        #pragma unroll
        for (int r = 0; r < 4; r++)
            #pragma unroll
            for (int m4 = 0; m4 < 4; m4++)
                hv[r][m4] = hs[(lane >> 4) * 4 + r][m4 * 16 + (lane & 15)];

        auto merge = [&](int p, float& r0, float& r1, int& pd_io, int& rs_io) {
            int pd = pd_io, rs = rs_io;
            #pragma unroll 1
            for (int e = 0; e < 16; e++) {
                int g = sb * 16 + e;
                int d = dsts[e];
                if (g == 0) {
                    pd = d;
                } else if (d != pd) {
                    float* Ap = A + (size_t)pd * 1024 + p * 512 + 2 * tid;
                    if (rs == 0) { atomicAdd(Ap, r0); atomicAdd(Ap + 1, r1); }
                    else         { *(float2*)Ap = make_float2(r0, r1); }
                    r0 = 0.f; r1 = 0.f; rs = g; pd = d;
                }
                float2 v = *(const float2*)&mbuf[e][2 * tid];
                r0 += v.x; r1 += v.y;
            }
            pd_io = pd; rs_io = rs;
        };

        for (int p = 0; p < 2; p++) {
            float yv[4][2];
            #pragma unroll
            for (int r = 0; r < 4; r++)
                #pragma unroll
                for (int kk = 0; kk < 2; kk++)
                    yv[r][kk] = ys[(lane >> 4) * 4 + r][p * 8 + w * 2 + kk] * 0.125f;

            #pragma unroll
            for (int nbl = 0; nbl < 8; nbl++) {
                int nb = p * 32 + w * 8 + nbl;
                bf16x8 bh0 = Bhf[(0 * 64 + nb) * 64 + lane];
                bf16x8 bl0 = Blf[(0 * 64 + nb) * 64 + lane];
                bf16x8 bh1 = Bhf[(1 * 64 + nb) * 64 + lane];
                bf16x8 bl1 = Blf[(1 * 64 + nb) * 64 + lane];
                f32x4 acc = {0.f, 0.f, 0.f, 0.f};
                acc = __builtin_amdgcn_mfma_f32_16x16x32_bf16(ah0, bh0, acc, 0, 0, 0);
                acc = __builtin_amdgcn_mfma_f32_16x16x32_bf16(al0, bh0, acc, 0, 0, 0);
                acc = __builtin_amdgcn_mfma_f32_16x16x32_bf16(ah0, bl0, acc, 0, 0, 0);
                acc = __builtin_amdgcn_mfma_f32_16x16x32_bf16(ah1, bh1, acc, 0, 0, 0);
                acc = __builtin_amdgcn_mfma_f32_16x16x32_bf16(al1, bh1, acc, 0, 0, 0);
                acc = __builtin_amdgcn_mfma_f32_16x16x32_bf16(ah1, bl1, acc, 0, 0, 0);
                #pragma unroll
                for (int r = 0; r < 4; r++) {
                    float m = acc[r] * yv[r][nbl >> 2] * hv[r][nbl & 3];
                    mbuf[(lane >> 4) * 4 + r][(w * 8 + nbl) * 16 + (lane & 15)] = m;
                }
            }
            __syncthreads();             // mbuf ready for merge
            if (p == 0) {
                int pd0 = prev_d, rs0 = run_start;
                merge(0, r00, r01, pd0, rs0);          // state discarded
            } else {
                merge(1, r10, r11, prev_d, run_start); // commits state
            }
            __syncthreads();             // merge done; mbuf reusable
        }
    }
    // final runs continue into next block -> atomic
    {
        float* Ap = A + (size_t)prev_d * 1024 + 2 * tid;
        atomicAdd(Ap, r00); atomicAdd(Ap + 1, r01);
        float* Ap1 = A + (size_t)prev_d * 1024 + 512 + 2 * tid;
        atomicAdd(Ap1, r10); atomicAdd(Ap1 + 1, r11);
    }
}

// ---- l=0 node update --------------------------------------------------------
__global__ __launch_bounds__(256) void k_update0(
    const float* __restrict__ A, const float* __restrict__ h0,
    const float* __restrict__ Wsc, const float* __restrict__ pw,
    const float* __restrict__ read1_w, const int* __restrict__ species,
    float* __restrict__ h2, float* __restrict__ node_es)
{
    __shared__ float h0s[4][64];
    int wave = threadIdx.x >> 6, lane = threadIdx.x & 63;
    int n = blockIdx.x * 4 + wave;
    h0s[wave][lane] = h0[(size_t)n*64 + lane];
    __syncthreads();
    int sp = species[n];
    const float* W = Wsc + (size_t)sp*4096;
    float sc0 = 0.f;
    #pragma unroll
    for (int c = 0; c < 64; c++) sc0 = fmaf(h0s[wave][c], W[c*64+lane], sc0);
    float a[16], inv2 = 0.f;
    #pragma unroll
    for (int kk = 0; kk < 16; kk++) {
        a[kk] = A[(size_t)n*1024 + kk*64 + lane];
        inv2 = fmaf(a[kk], a[kk], inv2);
    }
    float inv3 = inv2 * a[0];
    float hn0 = a[0]*pw[lane] + inv2*pw[64+lane] + inv3*pw[128+lane] + sc0;
    h2[(size_t)n*64 + lane] = hn0;
    float r = hn0 * read1_w[lane];
    #pragma unroll
    for (int off = 32; off; off >>= 1) r += __shfl_down(r, off, 64);
    if (lane == 0) node_es[n] += r;
}

// ---- l=1: only readout contribution ----------------------------------------
__global__ __launch_bounds__(256) void k_update1(
    const float* __restrict__ A, const float* __restrict__ h2,
    const float* __restrict__ Wsc, const float* __restrict__ pw,
    const float* __restrict__ Wa, const float* __restrict__ wb,
    const int* __restrict__ species, float* __restrict__ node_es)
{
    __shared__ float h0s[4][64];
    __shared__ float hns[4][64];
    int wave = threadIdx.x >> 6, lane = threadIdx.x & 63;
    int n = blockIdx.x * 4 + wave;
    h0s[wave][lane] = h2[(size_t)n*64 + lane];
    __syncthreads();
    int sp = species[n];
    const float* W = Wsc + (size_t)sp*4096;
    float sc0 = 0.f;
    #pragma unroll
    for (int c = 0; c < 64; c++) sc0 = fmaf(h0s[wave][c], W[c*64+lane], sc0);
    float a[16], inv2 = 0.f;
    #pragma unroll
    for (int kk = 0; kk < 16; kk++) {
        a[kk] = A[(size_t)n*1024 + kk*64 + lane];
        inv2 = fmaf(a[kk], a[kk], inv2);
    }
    float inv3 = inv2 * a[0];
    float hn0 = a[0]*pw[lane] + inv2*pw[64+lane] + inv3*pw[128+lane] + sc0;
    hns[wave][lane] = hn0;
    __syncthreads();
    float contrib = 0.f;
    if (lane < 16) {
        float aj = 0.f;
        #pragma unroll
        for (int f = 0; f < 64; f++) aj = fmaf(hns[wave][f], Wa[f*16+lane], aj);
        contrib = silu_f(aj) * wb[lane];
    }
    #pragma unroll
    for (int off = 8; off; off >>= 1) contrib += __shfl_down(contrib, off, 64);
    if (lane == 0) node_es[n] += contrib;
}

__global__ __launch_bounds__(256) void k_reduce(
    const float* __restrict__ node_es, const int* __restrict__ batch,
    float* __restrict__ out)
{
    __shared__ float bins[NG];
    if (threadIdx.x < NG) bins[threadIdx.x] = 0.f;
    __syncthreads();
    for (int n = blockIdx.x*256 + threadIdx.x; n < NN; n += gridDim.x*256)
        atomicAdd(&bins[batch[n]], node_es[n]);
    __syncthreads();
    if (threadIdx.x < NG) atomicAdd(&out[threadIdx.x], bins[threadIdx.x]);
}

extern "C" void kernel_launch(void* const* d_in, const int* in_sizes, int n_in,
                              void* d_out, int out_size, void* d_ws, size_t ws_size,
                              hipStream_t stream)
{
    const float* positions = (const float*)d_in[0];
    const float* atomic_energies = (const float*)d_in[1];
    const float* W_embed  = (const float*)d_in[2];
    const float* rW1      = (const float*)d_in[3];
    const float* rW2      = (const float*)d_in[4];
    const float* rW3      = (const float*)d_in[5];
    const float* rWout    = (const float*)d_in[6];
    const float* Wsc      = (const float*)d_in[7];
    const float* pw       = (const float*)d_in[8];
    const float* read1_w  = (const float*)d_in[9];
    const float* read2_Wa = (const float*)d_in[10];
    const float* read2_wb = (const float*)d_in[11];
    const int* species    = (const int*)d_in[12];
    const int* edge_index = (const int*)d_in[13];
    const int* batch      = (const int*)d_in[14];
    float* out = (float*)d_out;

    char* w = (char*)d_ws;
    float* Y     = (float*)w;  w += (size_t)NE*16*4;
    float* feats = (float*)w;  w += (size_t)NE*8*4;
    float* T3    = (float*)w;  w += (size_t)NE*64*4;
    float* h0    = (float*)w;  w += (size_t)NN*64*4;
    float* h2    = (float*)w;  w += (size_t)NN*64*4;
    float* A     = (float*)w;  w += (size_t)NN*1024*4;
    float* node_es = (float*)w; w += (size_t)NN*4;
    int* deg     = (int*)w;    w += (size_t)NN*4;
    int* cursor  = (int*)w;    w += (size_t)NN*4;
    int* sSrc    = (int*)w;    w += (size_t)NE*4;
    int* sDst    = (int*)w;    w += (size_t)NE*4;
    unsigned short* Bh = (unsigned short*)w; w += (size_t)2*8192*8*2;
    unsigned short* Bl = (unsigned short*)w; w += (size_t)2*8192*8*2;

    // ---- counting sort by dst
    hipMemsetAsync(deg, 0, (size_t)NN*4, stream);
    k_count<<<NE/256, 256, 0, stream>>>(edge_index, deg);
    k_scan<<<1, 256, 0, stream>>>(deg, cursor);
    k_fill<<<NE/256, 256, 0, stream>>>(edge_index, cursor, sSrc, sDst);

    k_wprep<<<64, 256, 0, stream>>>(rWout, Bh, Bl);
    k_edge_geom<<<NE/256, 256, 0, stream>>>(positions, sSrc, sDst, Y, feats);
    k_h_init<<<NN*64/256, 256, 0, stream>>>(W_embed, atomic_energies, species, h0, node_es);

    // layer 0
    hipMemsetAsync(A, 0, (size_t)NN*1024*4, stream);
    k_radial<<<2048, 256, 0, stream>>>(feats, rW1, rW2, rW3, T3);
    k_message<<<NE/64, 256, 0, stream>>>(T3, Bh, Bl, Y, h0, sSrc, sDst, A);
    k_update0<<<NN/4, 256, 0, stream>>>(A, h0, Wsc, pw, read1_w, species, h2, node_es);

    // layer 1
    hipMemsetAsync(A, 0, (size_t)NN*1024*4, stream);
    k_radial<<<2048, 256, 0, stream>>>(feats, rW1 + 8*64, rW2 + 64*64, rW3 + 64*64, T3);
    k_message<<<NE/64, 256, 0, stream>>>(T3, Bh + (size_t)8192*8, Bl + (size_t)8192*8,
                                         Y, h2, sSrc, sDst, A);
    k_update1<<<NN/4, 256, 0, stream>>>(A, h2, Wsc + 10*4096, pw + 192,
                                        read2_Wa, read2_wb, species, node_es);

    hipMemsetAsync(d_out, 0, NG*sizeof(float), stream);
    k_reduce<<<64, 256, 0, stream>>>(node_es, batch, out);
}